// Round 11
// baseline (150.870 us; speedup 1.0000x reference)
//
#include <hip/hip_runtime.h>

// Problem constants (from reference)
#define M_PTS   16385     // int(65536*0.25)+1
#define K_NB    16
#define CIN_C   256
#define COUT_C  512
#define N_ROWS  65536
#define LN_EPS  1e-5f

#define OUT_XYZ_ELEMS (M_PTS * 3)                      // 49155
#define OUT_FEAT_OFF  OUT_XYZ_ELEMS
#define OUT_NOFF_IDX  (OUT_XYZ_ELEMS + M_PTS * COUT_C) // 8438275

// prep grid: 2048 grid-strided LN blocks (2 rows/wave/iter x 4 iters)
//          + 512 blocks weight/xyz prep
#define LN_BLOCKS   2048
#define PREP_BLOCKS 512

// main grid: 513 blocks x 32 points; 512 threads = 8 waves x 64 output cols
#define NBLK 513
#define PPB  32

#define B_SCALE 16.0f     // lin_w pre-scale (keeps e4m3 out of subnormals)
#define B_INV   0.0625f
#define SCL_ONE 0x7F7F7F7F  // e8m0 127 = 2^0 in every byte -> identity scale

#define AROW_B 272        // A-tile row stride in LDS BYTES (256 fp8 + 16 pad)

typedef __attribute__((ext_vector_type(4))) float f32x4;
typedef __attribute__((ext_vector_type(8))) int   i32x8;
typedef __attribute__((ext_vector_type(2))) unsigned int uint2v;

// Full-wave (64-lane) float sum on the VALU pipe via DPP — no DS-pipe ops.
__device__ __forceinline__ float wave_sum64(float v) {
  v += __int_as_float(__builtin_amdgcn_update_dpp(0, __float_as_int(v), 0xB1, 0xF, 0xF, false));
  v += __int_as_float(__builtin_amdgcn_update_dpp(0, __float_as_int(v), 0x4E, 0xF, 0xF, false));
  v += __int_as_float(__builtin_amdgcn_update_dpp(0, __float_as_int(v), 0x141, 0xF, 0xF, false));
  v += __int_as_float(__builtin_amdgcn_update_dpp(0, __float_as_int(v), 0x140, 0xF, 0xF, false));
  v += __int_as_float(__builtin_amdgcn_update_dpp(0, __float_as_int(v), 0x142, 0xA, 0xF, false));
  v += __int_as_float(__builtin_amdgcn_update_dpp(0, __float_as_int(v), 0x143, 0xC, 0xF, false));
  return __int_as_float(__builtin_amdgcn_readlane(__float_as_int(v), 63));
}

// LayerNorm the wave's 256-ch row (lane holds ch 4L..4L+3) and pack to 4 fp8.
// Bit-identical math to the verified R1/R10 version.
__device__ __forceinline__ int ln_pack(float4 g, float4 nw, float4 nb) {
  float s1 = (g.x + g.y) + (g.z + g.w);
  float s2 = g.x * g.x + g.y * g.y + g.z * g.z + g.w * g.w;
  float S1 = wave_sum64(s1);
  float S2 = wave_sum64(s2);
  float mu  = S1 * (1.0f / 256.0f);
  float var = fmaf(-mu, mu, S2 * (1.0f / 256.0f));
  float rs  = rsqrtf(var + LN_EPS);
  float a = fmaf((g.x - mu) * rs, nw.x, nb.x);
  float b = fmaf((g.y - mu) * rs, nw.y, nb.y);
  float c = fmaf((g.z - mu) * rs, nw.z, nb.z);
  float d = fmaf((g.w - mu) * rs, nw.w, nb.w);
  int v = __builtin_amdgcn_cvt_pk_fp8_f32(a, b, 0, false);   // bytes 0,1
  v = __builtin_amdgcn_cvt_pk_fp8_f32(c, d, v, true);        // bytes 2,3
  return v;
}

// Prep (LN part R10-verified; B-swizzle re-derived for 64-col waves):
//  blocks [0, 2048): LayerNorm + fp8-pack ALL 65536 feats rows into the 16 MB
//    LINEAR table (byte c = channel c).
//  blocks [2048, 2560): lin_w -> fp8 x16 swizzle for the K=128 B-fragment with
//    8 waves x 64 cols, n_xyz gather, n_offset.
__global__ void prep_kernel(const float* __restrict__ lin_w,
                            const float* __restrict__ xyz,
                            const float* __restrict__ feats,
                            const float* __restrict__ norm_w,
                            const float* __restrict__ norm_b,
                            const int*   __restrict__ samp_idx,
                            const int*   __restrict__ offset,
                            unsigned char* __restrict__ lw8,
                            unsigned char* __restrict__ tab,
                            float*  __restrict__ out) {
  int bx = blockIdx.x;
  if (bx < LN_BLOCKS) {
    const int lane = threadIdx.x & 63;
    const int gw   = (bx << 2) + (threadIdx.x >> 6);  // global wave 0..8191
    const float4 nw = ((const float4*)norm_w)[lane];
    const float4 nb = ((const float4*)norm_b)[lane];
    const float4* f4 = (const float4*)feats;
    const int wo = lane << 2;                         // LINEAR row layout
#pragma unroll
    for (int i = 0; i < 4; ++i) {
      const int ra = (i << 14) + (gw << 1);           // rows ra, ra+1
      float4 ga = f4[(size_t)ra * 64 + lane];
      float4 gb = f4[(size_t)(ra + 1) * 64 + lane];
      int pka = ln_pack(ga, nw, nb);                  // independent chains —
      int pkb = ln_pack(gb, nw, nb);                  // scheduler interleaves
      *(int*)(tab + ((size_t)ra << 8) + wo)       = pka;
      *(int*)(tab + ((size_t)(ra + 1) << 8) + wo) = pkb;
    }
    return;
  }
  int tid = (bx - LN_BLOCKS) * 256 + threadIdx.x;
  if (tid < COUT_C * CIN_C) {
    int o = tid >> 8;          // 0..511  (cout)
    int c = tid & 255;         // 0..255  (cin)
    // K=128 B-fragment, 64-col waves: wave w = o>>6 owns cols [w*64,+64) as
    // 4 groups of 16 (g = (o>>4)&3). MFMA(ks = c>>7) lane ((c>>5)&3)*16+(o&15)
    // supplies col (o&15), k-byte c&31. Lane's 32 B contiguous:
    // pos = w*16384 + g*4096 + ks*2048 + lane*32 + b
    int lanei = (((c >> 5) & 3) << 4) | (o & 15);
    int pos = ((o >> 6) << 14) | (((o >> 4) & 3) << 12) | ((c >> 7) << 11)
            | (lanei << 5) | (c & 31);
    int pk = __builtin_amdgcn_cvt_pk_fp8_f32(lin_w[tid] * B_SCALE, 0.0f, 0, false);
    lw8[pos] = (unsigned char)(pk & 0xFF);
  }
  if (tid < OUT_XYZ_ELEMS) {
    int p = tid / 3;
    int c = tid - p * 3;
    out[tid] = xyz[(size_t)samp_idx[p] * 3 + c];
  }
  if (tid == 0) out[OUT_NOFF_IDX] = (float)(offset[0] / 4 + 1);
}

// One 256 B table row -> LDS via direct DMA (4 B/lane, wave-uniform LDS base).
// src = tabL + preshifted row byte offset (Kidx holds idx<<8).
__device__ __forceinline__ void load_row(const unsigned char* __restrict__ src,
                                         unsigned char* ldsrow) {
  __builtin_amdgcn_global_load_lds(
      (const __attribute__((address_space(1))) unsigned int*)src,
      (__attribute__((address_space(3))) unsigned int*)ldsrow,
      4, 0, 0);
}

// 16-row maxpool reduce on the VALU pipe via permlane-swap builtins
// (R9/R10-verified bit-exact). After this, every lane holds the max over all
// 16 rows of column (lane&15) of its group.
__device__ __forceinline__ float pool16(f32x4 a) {
  float v = fmaxf(fmaxf(a[0], a[1]), fmaxf(a[2], a[3]));
  uint2v r = __builtin_amdgcn_permlane16_swap(__float_as_uint(v), __float_as_uint(v), false, false);
  v = fmaxf(__uint_as_float(r.x), __uint_as_float(r.y));
  uint2v s = __builtin_amdgcn_permlane32_swap(__float_as_uint(v), __float_as_uint(v), false, false);
  return fmaxf(__uint_as_float(s.x), __uint_as_float(s.y));
}

// GEMM one point's 16x256 fp8 A-tile against the wave's 64-col B registers
// (4 groups of 16 cols) with the MX-scaled K=128 MFMA, then maxpool over the
// 16 rows. A-fragments (ak0/ak1) are read ONCE and feed all 4 groups — this
// halves block-level LDS traffic vs the 16-wave/32-col config. Per-column
// MFMA chain order identical to R10 -> bitwise-identical outputs.
// Returns the store value for this lane (group = quad), pre-B_INV.
__device__ __forceinline__ float gemm_pool64(const unsigned char* rowbase,
                                             const i32x8 Breg[4][2], int quad) {
  i32x8 ak0 = *(const i32x8*)(rowbase);        // ks=0: channels [q32, q32+32)
  i32x8 ak1 = *(const i32x8*)(rowbase + 128);  // ks=1: + 128
  f32x4 a0 = {0.f, 0.f, 0.f, 0.f}, a1 = {0.f, 0.f, 0.f, 0.f};
  f32x4 a2 = {0.f, 0.f, 0.f, 0.f}, a3 = {0.f, 0.f, 0.f, 0.f};
  a0 = __builtin_amdgcn_mfma_scale_f32_16x16x128_f8f6f4(
         ak0, Breg[0][0], a0, 0, 0, 0, SCL_ONE, 0, SCL_ONE);
  a1 = __builtin_amdgcn_mfma_scale_f32_16x16x128_f8f6f4(
         ak0, Breg[1][0], a1, 0, 0, 0, SCL_ONE, 0, SCL_ONE);
  a2 = __builtin_amdgcn_mfma_scale_f32_16x16x128_f8f6f4(
         ak0, Breg[2][0], a2, 0, 0, 0, SCL_ONE, 0, SCL_ONE);
  a3 = __builtin_amdgcn_mfma_scale_f32_16x16x128_f8f6f4(
         ak0, Breg[3][0], a3, 0, 0, 0, SCL_ONE, 0, SCL_ONE);
  a0 = __builtin_amdgcn_mfma_scale_f32_16x16x128_f8f6f4(
         ak1, Breg[0][1], a0, 0, 0, 0, SCL_ONE, 0, SCL_ONE);
  a1 = __builtin_amdgcn_mfma_scale_f32_16x16x128_f8f6f4(
         ak1, Breg[1][1], a1, 0, 0, 0, SCL_ONE, 0, SCL_ONE);
  a2 = __builtin_amdgcn_mfma_scale_f32_16x16x128_f8f6f4(
         ak1, Breg[2][1], a2, 0, 0, 0, SCL_ONE, 0, SCL_ONE);
  a3 = __builtin_amdgcn_mfma_scale_f32_16x16x128_f8f6f4(
         ak1, Breg[3][1], a3, 0, 0, 0, SCL_ONE, 0, SCL_ONE);
  float v0 = pool16(a0);
  float v1 = pool16(a1);
  float v2 = pool16(a2);
  float v3 = pool16(a3);
  // Lane (quad,lcol) stores col w*64 + quad*16 + lcol -> select group quad.
  return (quad == 0) ? v0 : (quad == 1) ? v1 : (quad == 2) ? v2 : v3;
}

// Fused main — 8 waves x 64 cols (halved LDS-read redundancy vs R10):
// 512 threads, 2 points/iter, 4-deep LDS rotation, counted-vmcnt 6/4/2, one
// raw barrier per iteration, runtime min() tail, NBLK=513. Wave w stages rows
// {w, 8+w} of both points (4 global_load_lds/iter) and owns output cols
// [w*64, w*64+64). Stores are full-wave (64 cols per point).
__global__ __launch_bounds__(512, 4)
void td_main(const unsigned char* __restrict__ tab,
             const unsigned char* __restrict__ lw8,
             const int*    __restrict__ knn,
             float* __restrict__ out) {
  __shared__ __align__(16) unsigned char A8[4][32][AROW_B]; // 34816 B
  __shared__ int Kidx[PPB * K_NB];                          // 2048 B

  const int tid  = threadIdx.x;
  const int lane = tid & 63;
  const int w    = tid >> 6;        // wave 0..7 = 64-col chunk
  const int quad = lane >> 4;
  const int lcol = lane & 15;

  const int pstart = blockIdx.x * PPB;
  const int npts   = min(pstart + PPB, M_PTS) - pstart;
  if (npts <= 0) return;

  // Stage this block's knn indices, PRE-SHIFTED to row byte offsets (idx*256)
  for (int i = tid; i < npts * K_NB; i += 512)
    Kidx[i] = knn[pstart * K_NB + i] << 8;

  // Persistent fp8 B chunk: Breg[g][ks], 64 VGPRs, 32 B/lane contiguous loads
  i32x8 Breg[4][2];
  {
    const unsigned char* base = lw8 + (w << 14) + lane * 32;
#pragma unroll
    for (int g = 0; g < 4; ++g)
#pragma unroll
      for (int ks = 0; ks < 2; ++ks) {
        Breg[g][ks] = *(const i32x8*)(base + (g << 12) + (ks << 11));
        asm volatile("" : "+v"(Breg[g][ks]));   // opaque: cannot be re-sunk
      }
  }

  const unsigned char* tabL = tab + (lane << 2);  // hoisted per-lane base

  __syncthreads();                  // Kidx visible (full sync, once)

  // Preload pair 0 into buffer 0: rows {w, 8+w} of points 0 and 1
  {
    int p1 = min(1, npts - 1);
    load_row(tabL + (unsigned)Kidx[w],                 &A8[0][w][0]);
    load_row(tabL + (unsigned)Kidx[8 + w],             &A8[0][8 + w][0]);
    load_row(tabL + (unsigned)Kidx[p1 * K_NB + w],     &A8[0][16 + w][0]);
    load_row(tabL + (unsigned)Kidx[p1 * K_NB + 8 + w], &A8[0][24 + w][0]);
  }

  const int nit = (npts + 1) >> 1;
  for (int it = 0; it < nit; ++it) {
    const int pa = 2 * it, pb = 2 * it + 1;

    // Prefetch pair it+1 into buffer (it+1)&3 (crosses the barrier un-drained)
    if (it + 1 < nit) {
      int qa = min(pa + 2, npts - 1), qb = min(pa + 3, npts - 1);
      int b = (it + 1) & 3;
      load_row(tabL + (unsigned)Kidx[qa * K_NB + w],     &A8[b][w][0]);
      load_row(tabL + (unsigned)Kidx[qa * K_NB + 8 + w], &A8[b][8 + w][0]);
      load_row(tabL + (unsigned)Kidx[qb * K_NB + w],     &A8[b][16 + w][0]);
      load_row(tabL + (unsigned)Kidx[qb * K_NB + 8 + w], &A8[b][24 + w][0]);
    }

    // Counted vmcnt (in-order VMEM retire). Queue at the wait point:
    //   steady: [L(it)x4, S(it-1)x2, L(it+1)x4] -> retire L(it): vmcnt(6)
    //   it==0:  [L(0)x4, L(1)x4]                -> vmcnt(4)
    //   last:   [L(it)x4, S(it-1)x2]            -> vmcnt(2)
    if (it == 0) {
      if (nit > 1) asm volatile("s_waitcnt vmcnt(4)" ::: "memory");
      else         asm volatile("s_waitcnt vmcnt(0)" ::: "memory");
    } else if (it + 1 < nit) {
      asm volatile("s_waitcnt vmcnt(6)" ::: "memory");
    } else {
      asm volatile("s_waitcnt vmcnt(2)" ::: "memory");
    }
    __builtin_amdgcn_s_barrier();   // all 32 rows of buffer it&3 landed

    const unsigned char* Ab = &A8[it & 3][0][0];
    const unsigned char* rowb = Ab + lcol * AROW_B + quad * 32;

    // GEMM + maxpool, point a then point b; full-wave 64-col stores.
    float va = gemm_pool64(rowb, Breg, quad);
    float* outa = out + OUT_FEAT_OFF + (size_t)(pstart + pa) * COUT_C + w * 64;
    outa[lane] = va * B_INV;

    float vb = gemm_pool64(rowb + 16 * AROW_B, Breg, quad);
    if (pb < npts) {
      float* outb = out + OUT_FEAT_OFF + (size_t)(pstart + pb) * COUT_C + w * 64;
      outb[lane] = vb * B_INV;
    }
    // Buffer (it+1)&3 was last read at it-3: >=3 barriers separate that read
    // from the prefetch writes above -> single barrier per iteration is safe.
  }
}

extern "C" void kernel_launch(void* const* d_in, const int* in_sizes, int n_in,
                              void* d_out, int out_size, void* d_ws, size_t ws_size,
                              hipStream_t stream) {
  const float* xyz      = (const float*)d_in[0];
  const float* feats    = (const float*)d_in[1];
  const float* norm_w   = (const float*)d_in[2];
  const float* norm_b   = (const float*)d_in[3];
  const float* lin_w    = (const float*)d_in[4];
  const int*   samp_idx = (const int*)d_in[5];
  const int*   knn      = (const int*)d_in[6];
  const int*   offset   = (const int*)d_in[7];
  float* out = (float*)d_out;
  unsigned char* lw8 = (unsigned char*)d_ws;               // 128 KB fp8 weights
  unsigned char* tab = (unsigned char*)d_ws + (1 << 17);   // 16 MB normed-fp8 feats

  prep_kernel<<<LN_BLOCKS + PREP_BLOCKS, 256, 0, stream>>>(
      lin_w, xyz, feats, norm_w, norm_b, samp_idx, offset, lw8, tab, out);

  td_main<<<NBLK, 512, 0, stream>>>(tab, lw8, knn, out);
}